// Round 1
// 3048.579 us; speedup vs baseline: 2.0420x; 2.0420x over previous
//
#include <hip/hip_runtime.h>

#define HID   256
#define BATCH 2048
#define NGATE 1024
#define BM    16        // batch rows per workgroup
#define NWG   128       // BATCH/BM -> one WG per CU on 128 CUs
#define TPB   1024      // 16 waves
#define LDS_BYTES 147456  // 16KB h double-buffer + 128KB weight cache

typedef __attribute__((ext_vector_type(8))) short bf16x8;
typedef __attribute__((ext_vector_type(4))) float f32x4;

__device__ __forceinline__ unsigned short f2bf(float x){
  unsigned int u = __builtin_bit_cast(unsigned int, x);
  u += 0x7fffu + ((u >> 16) & 1u);          // RNE
  return (unsigned short)(u >> 16);
}
__device__ __forceinline__ float fsigm(float x){
  return __builtin_amdgcn_rcpf(1.0f + __expf(-x));
}
__device__ __forceinline__ float ftanh_(float x){
  return fmaf(2.0f, __builtin_amdgcn_rcpf(1.0f + __expf(-2.0f*x)), -1.0f);
}

// Pack W_ih and (W_ih+W_hh) into MFMA B-fragment order:
// frag(nt,kt) is 1024B, lane-linear: lane l holds W[nt*16 + (l&15)][kt*32 + (l>>4)*8 + j]
__global__ void pack_kernel(const float* __restrict__ Wih, const float* __restrict__ Whh,
                            const float* __restrict__ bih, const float* __restrict__ bhh,
                            unsigned short* __restrict__ Wih_p,
                            unsigned short* __restrict__ Wsum_p,
                            float* __restrict__ bias){
  int tid = blockIdx.x * blockDim.x + threadIdx.x;   // 0..262143
  int j  = tid & 7;
  int ln = (tid >> 3) & 63;
  int kt = (tid >> 9) & 7;
  int nt = tid >> 12;
  int n = nt*16 + (ln & 15);
  int k = kt*32 + (ln >> 4)*8 + j;
  float wih = Wih[n*HID + k];
  float whh = Whh[n*HID + k];
  Wih_p[tid]  = f2bf(wih);
  Wsum_p[tid] = f2bf(wih + whh);
  if (tid < NGATE) bias[tid] = bih[tid] + bhh[tid];
}

// One LSTM time step. Wave w owns hidden units [16w,16w+16) for all 4 gates.
// B-fragment sources per wave: kt 0-1 registers, kt 2-3 LDS, kt 4-7 streamed from L2.
template<bool FIRST>
__device__ __forceinline__ void lstm_step(
    int t, int T, int g, int w, int l, int l15, int lq,
    const unsigned short* __restrict__ hcur,   // LDS, A-frag layout, 4096 ushorts
    unsigned short* __restrict__ hnext,        // LDS
    const unsigned short* __restrict__ wl,     // LDS weight cache base
    const bf16x8 (&wregs)[4][2],
    const unsigned short* __restrict__ Wih_p,
    const unsigned short* __restrict__ Wsum_p,
    const float (&bv)[4], float (&cs)[4],
    float* __restrict__ out)
{
  const f32x4 z = {0.f,0.f,0.f,0.f};
  f32x4 acc[4] = {z,z,z,z};

  if constexpr (FIRST){
    // t==0 uses W_ih: stream all 8 k-tiles (one-time)
    #pragma unroll
    for (int kt = 0; kt < 8; ++kt){
      bf16x8 av = *(const bf16x8*)&hcur[kt*512 + l*8];
      #pragma unroll
      for (int ga = 0; ga < 4; ++ga){
        bf16x8 bfr = *(const bf16x8*)(Wih_p + (size_t)((ga*16 + w)*8 + kt)*512 + l*8);
        acc[ga] = __builtin_amdgcn_mfma_f32_16x16x32_bf16(av, bfr, acc[ga], 0, 0, 0);
      }
    }
  } else {
    // issue first half of the streamed loads (kt 4-5) early
    bf16x8 bsA[4][2];
    #pragma unroll
    for (int ks = 0; ks < 2; ++ks)
      #pragma unroll
      for (int ga = 0; ga < 4; ++ga)
        bsA[ga][ks] = *(const bf16x8*)(Wsum_p + (size_t)((ga*16 + w)*8 + 4 + ks)*512 + l*8);

    // kt 0-1: register-resident weights
    #pragma unroll
    for (int kc = 0; kc < 2; ++kc){
      bf16x8 av = *(const bf16x8*)&hcur[kc*512 + l*8];
      #pragma unroll
      for (int ga = 0; ga < 4; ++ga)
        acc[ga] = __builtin_amdgcn_mfma_f32_16x16x32_bf16(av, wregs[ga][kc], acc[ga], 0, 0, 0);
    }

    // issue second half of streamed loads (kt 6-7)
    bf16x8 bsB[4][2];
    #pragma unroll
    for (int ks = 0; ks < 2; ++ks)
      #pragma unroll
      for (int ga = 0; ga < 4; ++ga)
        bsB[ga][ks] = *(const bf16x8*)(Wsum_p + (size_t)((ga*16 + w)*8 + 6 + ks)*512 + l*8);

    // kt 2-3: LDS-cached weights
    #pragma unroll
    for (int kc = 0; kc < 2; ++kc){
      bf16x8 av = *(const bf16x8*)&hcur[(2+kc)*512 + l*8];
      #pragma unroll
      for (int ga = 0; ga < 4; ++ga){
        bf16x8 bfr = *(const bf16x8*)&wl[((w*8) + ga*2 + kc)*512 + l*8];
        acc[ga] = __builtin_amdgcn_mfma_f32_16x16x32_bf16(av, bfr, acc[ga], 0, 0, 0);
      }
    }

    // kt 4-7: streamed weights
    #pragma unroll
    for (int ks = 0; ks < 2; ++ks){
      bf16x8 av = *(const bf16x8*)&hcur[(4+ks)*512 + l*8];
      #pragma unroll
      for (int ga = 0; ga < 4; ++ga)
        acc[ga] = __builtin_amdgcn_mfma_f32_16x16x32_bf16(av, bsA[ga][ks], acc[ga], 0, 0, 0);
    }
    #pragma unroll
    for (int ks = 0; ks < 2; ++ks){
      bf16x8 av = *(const bf16x8*)&hcur[(6+ks)*512 + l*8];
      #pragma unroll
      for (int ga = 0; ga < 4; ++ga)
        acc[ga] = __builtin_amdgcn_mfma_f32_16x16x32_bf16(av, bsB[ga][ks], acc[ga], 0, 0, 0);
    }
  }

  // Epilogue: C layout col = l&15 (unit), row = lq*4 + r. All 4 gates in-lane.
  const int u   = w*16 + l15;
  const int ktu = w >> 1;
  const int kgu = ((w & 1) << 1) | (l15 >> 3);
  const int ju  = l15 & 7;
  const int orow = FIRST ? 0 : (T - t);        // x_hat[0]=h_0, x_hat[T-t]=h_t
  float* __restrict__ orp = out + (size_t)orow * (BATCH*HID);
  const bool last = (t == T - 1);

  #pragma unroll
  for (int r = 0; r < 4; ++r){
    const int m = lq*4 + r;
    const float iv = fsigm (acc[0][r] + bv[0]);
    const float fv = fsigm (acc[1][r] + bv[1]);
    const float gv = ftanh_(acc[2][r] + bv[2]);
    const float ov = fsigm (acc[3][r] + bv[3]);
    const float cn = fv * cs[r] + iv * gv;
    cs[r] = cn;
    const float hv = ov * ftanh_(cn);
    // next step's A-frag element (row m, k = u)
    hnext[ktu*512 + (kgu*16 + m)*8 + ju] = f2bf(hv);
    const size_t gi = (size_t)(g*BM + m)*HID + u;
    orp[gi] = hv;
    if (last){
      out[(size_t)T*(BATCH*HID) + gi]       = hv;   // hf
      out[(size_t)(T + 1)*(BATCH*HID) + gi] = cn;   // cf
    }
  }
}

__global__ __launch_bounds__(TPB, 4)
void lstm_kernel(const float* __restrict__ h_in,
                 const unsigned short* __restrict__ Wih_p,
                 const unsigned short* __restrict__ Wsum_p,
                 const float* __restrict__ bias,
                 const int* __restrict__ seqlen,
                 float* __restrict__ out){
  extern __shared__ unsigned short lds[];
  unsigned short* hb = lds;           // [2][4096] h in A-frag layout (double buffer)
  unsigned short* wl = lds + 8192;    // [16 waves][8 frags][512] weight cache (kt 2-3)

  const int T   = seqlen[0];
  const int g   = blockIdx.x;
  const int tid = threadIdx.x;
  const int w   = tid >> 6;       // wave 0..15
  const int l   = tid & 63;
  const int l15 = l & 15;
  const int lq  = l >> 4;
  const int u   = w*16 + l15;     // hidden unit owned by this lane

  float bv[4];
  #pragma unroll
  for (int ga = 0; ga < 4; ++ga) bv[ga] = bias[ga*256 + u];

  // Register weight cache: kt 0-1 of each gate's fragment row (8 frags = 32 VGPR)
  bf16x8 wregs[4][2];
  #pragma unroll
  for (int ga = 0; ga < 4; ++ga)
    #pragma unroll
    for (int kc = 0; kc < 2; ++kc)
      wregs[ga][kc] = *(const bf16x8*)(Wsum_p + (size_t)((ga*16 + w)*8 + kc)*512 + l*8);

  // LDS weight cache: kt 2-3 (8 frags/wave, 128 KB total), loaded once
  #pragma unroll
  for (int ga = 0; ga < 4; ++ga)
    #pragma unroll
    for (int kc = 0; kc < 2; ++kc)
      *(bf16x8*)&wl[((w*8) + ga*2 + kc)*512 + l*8] =
        *(const bf16x8*)(Wsum_p + (size_t)((ga*16 + w)*8 + 2 + kc)*512 + l*8);

  // Stage t=0 input (x = h_in) into hb[0], A-frag layout (same offsets as epilogue)
  {
    const int ktu = w >> 1;
    const int kgu = ((w & 1) << 1) | (l15 >> 3);
    const int ju  = l15 & 7;
    #pragma unroll
    for (int r = 0; r < 4; ++r){
      const int m = lq*4 + r;
      hb[ktu*512 + (kgu*16 + m)*8 + ju] = f2bf(h_in[(size_t)(g*BM + m)*HID + u]);
    }
  }

  float cs[4] = {0.f, 0.f, 0.f, 0.f};
  __syncthreads();

  lstm_step<true>(0, T, g, w, l, l15, lq, hb, hb + 4096, wl, wregs, Wih_p, Wsum_p, bv, cs, out);
  __syncthreads();
  int buf = 1;
  for (int t = 1; t < T; ++t){
    lstm_step<false>(t, T, g, w, l, l15, lq,
                     hb + buf*4096, hb + (buf^1)*4096, wl, wregs, Wih_p, Wsum_p, bv, cs, out);
    __syncthreads();
    buf ^= 1;
  }
}

extern "C" void kernel_launch(void* const* d_in, const int* in_sizes, int n_in,
                              void* d_out, int out_size, void* d_ws, size_t ws_size,
                              hipStream_t stream) {
  const float* h_in = (const float*)d_in[0];
  const float* Wih  = (const float*)d_in[1];
  const float* Whh  = (const float*)d_in[2];
  const float* bih  = (const float*)d_in[3];
  const float* bhh  = (const float*)d_in[4];
  const int*   seq  = (const int*)  d_in[5];
  float* out = (float*)d_out;

  unsigned short* Wih_p  = (unsigned short*)d_ws;                    // 512 KB
  unsigned short* Wsum_p = Wih_p + (size_t)NGATE * HID;              // 512 KB
  float*          bias   = (float*)(Wsum_p + (size_t)NGATE * HID);   // 4 KB

  static bool attr_set = false;
  if (!attr_set){
    hipFuncSetAttribute((const void*)lstm_kernel,
                        hipFuncAttributeMaxDynamicSharedMemorySize, LDS_BYTES);
    attr_set = true;
  }

  pack_kernel<<<dim3((NGATE*HID)/256), dim3(256), 0, stream>>>(
      Wih, Whh, bih, bhh, Wih_p, Wsum_p, bias);

  lstm_kernel<<<dim3(NWG), dim3(TPB), LDS_BYTES, stream>>>(
      h_in, Wih_p, Wsum_p, bias, seq, out);
}

// Round 2
// 2689.845 us; speedup vs baseline: 2.3143x; 1.1334x over previous
//
#include <hip/hip_runtime.h>

#define HID   256
#define BATCH 2048
#define NGATE 1024
#define BM    16        // batch rows per workgroup
#define NWG   128       // BATCH/BM -> one WG per CU on 128 CUs
#define TPB   1024      // 16 waves
#define LDS_BYTES 147456  // 16KB h double-buffer + 128KB weight cache

typedef __attribute__((ext_vector_type(8))) short bf16x8;
typedef __attribute__((ext_vector_type(4))) float f32x4;

__device__ __forceinline__ unsigned short f2bf(float x){
  unsigned int u = __builtin_bit_cast(unsigned int, x);
  u += 0x7fffu + ((u >> 16) & 1u);          // RNE
  return (unsigned short)(u >> 16);
}
__device__ __forceinline__ float fsigm(float x){
  return __builtin_amdgcn_rcpf(1.0f + __expf(-x));
}
__device__ __forceinline__ float ftanh_(float x){
  return fmaf(2.0f, __builtin_amdgcn_rcpf(1.0f + __expf(-2.0f*x)), -1.0f);
}

// Pack W_ih and (W_ih+W_hh) into MFMA B-fragment order:
// frag(nt,kt) is 1024B, lane-linear: lane l holds W[nt*16 + (l&15)][kt*32 + (l>>4)*8 + j]
__global__ void pack_kernel(const float* __restrict__ Wih, const float* __restrict__ Whh,
                            const float* __restrict__ bih, const float* __restrict__ bhh,
                            unsigned short* __restrict__ Wih_p,
                            unsigned short* __restrict__ Wsum_p,
                            float* __restrict__ bias){
  int tid = blockIdx.x * blockDim.x + threadIdx.x;   // 0..262143
  int j  = tid & 7;
  int ln = (tid >> 3) & 63;
  int kt = (tid >> 9) & 7;
  int nt = tid >> 12;
  int n = nt*16 + (ln & 15);
  int k = kt*32 + (ln >> 4)*8 + j;
  float wih = Wih[n*HID + k];
  float whh = Whh[n*HID + k];
  Wih_p[tid]  = f2bf(wih);
  Wsum_p[tid] = f2bf(wih + whh);
  if (tid < NGATE) bias[tid] = bih[tid] + bhh[tid];
}

// One LSTM time step. Wave w owns hidden units [16w,16w+16) for all 4 gates.
// B-fragment sources per wave: kt 0-3 registers, kt 4-5 LDS, kt 6-7 streamed from L2.
template<bool FIRST>
__device__ __forceinline__ void lstm_step(
    int t, int T, int g, int w, int l, int l15, int lq,
    const unsigned short* __restrict__ hcur,   // LDS, A-frag layout, 4096 ushorts
    unsigned short* __restrict__ hnext,        // LDS
    const unsigned short* __restrict__ wl,     // LDS weight cache base
    const bf16x8 (&wregs)[4][4],
    const unsigned short* __restrict__ Wih_p,
    const unsigned short* __restrict__ Wsum_p,
    const float (&bv)[4], float (&cs)[4],
    float* __restrict__ out)
{
  const f32x4 z = {0.f,0.f,0.f,0.f};
  f32x4 acc[4] = {z,z,z,z};

  if constexpr (FIRST){
    // t==0 uses W_ih: stream all 8 k-tiles (one-time)
    #pragma unroll
    for (int kt = 0; kt < 8; ++kt){
      bf16x8 av = *(const bf16x8*)&hcur[kt*512 + l*8];
      #pragma unroll
      for (int ga = 0; ga < 4; ++ga){
        bf16x8 bfr = *(const bf16x8*)(Wih_p + (size_t)((ga*16 + w)*8 + kt)*512 + l*8);
        acc[ga] = __builtin_amdgcn_mfma_f32_16x16x32_bf16(av, bfr, acc[ga], 0, 0, 0);
      }
    }
  } else {
    // Issue ALL streamed loads (kt 6-7, 8 frags = 32 VGPRs in flight) up front,
    // then fence the scheduler so they cannot be sunk below the MFMA work.
    bf16x8 bs[4][2];
    #pragma unroll
    for (int ks = 0; ks < 2; ++ks)
      #pragma unroll
      for (int ga = 0; ga < 4; ++ga)
        bs[ga][ks] = *(const bf16x8*)(Wsum_p + (size_t)((ga*16 + w)*8 + 6 + ks)*512 + l*8);
    __builtin_amdgcn_sched_barrier(0);

    // kt 0-3: register-resident weights (16 MFMAs, no memory dependence)
    #pragma unroll
    for (int kc = 0; kc < 4; ++kc){
      bf16x8 av = *(const bf16x8*)&hcur[kc*512 + l*8];
      #pragma unroll
      for (int ga = 0; ga < 4; ++ga)
        acc[ga] = __builtin_amdgcn_mfma_f32_16x16x32_bf16(av, wregs[ga][kc], acc[ga], 0, 0, 0);
    }

    // kt 4-5: LDS-cached weights
    #pragma unroll
    for (int kc = 0; kc < 2; ++kc){
      bf16x8 av = *(const bf16x8*)&hcur[(4+kc)*512 + l*8];
      #pragma unroll
      for (int ga = 0; ga < 4; ++ga){
        bf16x8 bfr = *(const bf16x8*)&wl[((w*8) + ga*2 + kc)*512 + l*8];
        acc[ga] = __builtin_amdgcn_mfma_f32_16x16x32_bf16(av, bfr, acc[ga], 0, 0, 0);
      }
    }

    // kt 6-7: streamed weights (loads have had ~24 MFMAs of cover)
    #pragma unroll
    for (int ks = 0; ks < 2; ++ks){
      bf16x8 av = *(const bf16x8*)&hcur[(6+ks)*512 + l*8];
      #pragma unroll
      for (int ga = 0; ga < 4; ++ga)
        acc[ga] = __builtin_amdgcn_mfma_f32_16x16x32_bf16(av, bs[ga][ks], acc[ga], 0, 0, 0);
    }
  }

  // Epilogue: C layout col = l&15 (unit), row = lq*4 + r. All 4 gates in-lane.
  const int u   = w*16 + l15;
  const int ktu = w >> 1;
  const int kgu = ((w & 1) << 1) | (l15 >> 3);
  const int ju  = l15 & 7;
  const int orow = FIRST ? 0 : (T - t);        // x_hat[0]=h_0, x_hat[T-t]=h_t
  float* __restrict__ orp = out + (size_t)orow * (BATCH*HID);
  const bool last = (t == T - 1);

  #pragma unroll
  for (int r = 0; r < 4; ++r){
    const int m = lq*4 + r;
    const float iv = fsigm (acc[0][r] + bv[0]);
    const float fv = fsigm (acc[1][r] + bv[1]);
    const float gv = ftanh_(acc[2][r] + bv[2]);
    const float ov = fsigm (acc[3][r] + bv[3]);
    const float cn = fv * cs[r] + iv * gv;
    cs[r] = cn;
    const float hv = ov * ftanh_(cn);
    // next step's A-frag element (row m, k = u)
    hnext[ktu*512 + (kgu*16 + m)*8 + ju] = f2bf(hv);
    const size_t gi = (size_t)(g*BM + m)*HID + u;
    orp[gi] = hv;
    if (last){
      out[(size_t)T*(BATCH*HID) + gi]       = hv;   // hf
      out[(size_t)(T + 1)*(BATCH*HID) + gi] = cn;   // cf
    }
  }
}

__global__ __launch_bounds__(TPB, 4)
void lstm_kernel(const float* __restrict__ h_in,
                 const unsigned short* __restrict__ Wih_p,
                 const unsigned short* __restrict__ Wsum_p,
                 const float* __restrict__ bias,
                 const int* __restrict__ seqlen,
                 float* __restrict__ out){
  extern __shared__ unsigned short lds[];
  unsigned short* hb = lds;           // [2][4096] h in A-frag layout (double buffer)
  unsigned short* wl = lds + 8192;    // [16 waves][8 frags][512] weight cache (kt 4-5)

  const int T   = seqlen[0];
  const int g   = blockIdx.x;
  const int tid = threadIdx.x;
  const int w   = tid >> 6;       // wave 0..15
  const int l   = tid & 63;
  const int l15 = l & 15;
  const int lq  = l >> 4;
  const int u   = w*16 + l15;     // hidden unit owned by this lane

  float bv[4];
  #pragma unroll
  for (int ga = 0; ga < 4; ++ga) bv[ga] = bias[ga*256 + u];

  // Register weight cache: kt 0-3 of each gate's fragment row (16 frags = 64 VGPR)
  bf16x8 wregs[4][4];
  #pragma unroll
  for (int ga = 0; ga < 4; ++ga)
    #pragma unroll
    for (int kc = 0; kc < 4; ++kc)
      wregs[ga][kc] = *(const bf16x8*)(Wsum_p + (size_t)((ga*16 + w)*8 + kc)*512 + l*8);

  // LDS weight cache: kt 4-5 (8 frags/wave, 128 KB total), loaded once
  #pragma unroll
  for (int ga = 0; ga < 4; ++ga)
    #pragma unroll
    for (int kc = 0; kc < 2; ++kc)
      *(bf16x8*)&wl[((w*8) + ga*2 + kc)*512 + l*8] =
        *(const bf16x8*)(Wsum_p + (size_t)((ga*16 + w)*8 + 4 + kc)*512 + l*8);

  // Stage t=0 input (x = h_in) into hb[0], A-frag layout (same offsets as epilogue)
  {
    const int ktu = w >> 1;
    const int kgu = ((w & 1) << 1) | (l15 >> 3);
    const int ju  = l15 & 7;
    #pragma unroll
    for (int r = 0; r < 4; ++r){
      const int m = lq*4 + r;
      hb[ktu*512 + (kgu*16 + m)*8 + ju] = f2bf(h_in[(size_t)(g*BM + m)*HID + u]);
    }
  }

  float cs[4] = {0.f, 0.f, 0.f, 0.f};
  __syncthreads();

  lstm_step<true>(0, T, g, w, l, l15, lq, hb, hb + 4096, wl, wregs, Wih_p, Wsum_p, bv, cs, out);
  __syncthreads();
  int buf = 1;
  for (int t = 1; t < T; ++t){
    lstm_step<false>(t, T, g, w, l, l15, lq,
                     hb + buf*4096, hb + (buf^1)*4096, wl, wregs, Wih_p, Wsum_p, bv, cs, out);
    __syncthreads();
    buf ^= 1;
  }
}

extern "C" void kernel_launch(void* const* d_in, const int* in_sizes, int n_in,
                              void* d_out, int out_size, void* d_ws, size_t ws_size,
                              hipStream_t stream) {
  const float* h_in = (const float*)d_in[0];
  const float* Wih  = (const float*)d_in[1];
  const float* Whh  = (const float*)d_in[2];
  const float* bih  = (const float*)d_in[3];
  const float* bhh  = (const float*)d_in[4];
  const int*   seq  = (const int*)  d_in[5];
  float* out = (float*)d_out;

  unsigned short* Wih_p  = (unsigned short*)d_ws;                    // 512 KB
  unsigned short* Wsum_p = Wih_p + (size_t)NGATE * HID;              // 512 KB
  float*          bias   = (float*)(Wsum_p + (size_t)NGATE * HID);   // 4 KB

  static bool attr_set = false;
  if (!attr_set){
    hipFuncSetAttribute((const void*)lstm_kernel,
                        hipFuncAttributeMaxDynamicSharedMemorySize, LDS_BYTES);
    attr_set = true;
  }

  pack_kernel<<<dim3((NGATE*HID)/256), dim3(256), 0, stream>>>(
      Wih, Whh, bih, bhh, Wih_p, Wsum_p, bias);

  lstm_kernel<<<dim3(NWG), dim3(TPB), LDS_BYTES, stream>>>(
      h_in, Wih_p, Wsum_p, bias, seq, out);
}